// Round 6
// baseline (193.300 us; speedup 1.0000x reference)
//
#include <hip/hip_runtime.h>

// GateLoopOperator, MI355X. Round 6: fuse k_gemm2+k_S into one GEMM
//   S[m,n] = sum_{c,k2,x,y} Ano[c,k2,x,y,n] * k[m,cx] * v[m,k2y]
// with the A operand (k x v outer product) built in-register, B = Ano rows
// (contiguous, n-minor) staged bf16 per (x) panel, double-buffered.
//
// Pipeline:
//  k_prep : A2[m][1536] bf16 = [hi(xp) | hi(xp) | lo(xp)]
//  k_cvtW : Bw[j][1536] bf16 = [hi(W) | lo | hi] (pre-permuted rows)
//  k_kqv3 : k/q/v f32 = A2 @ Bw^T (split-bf16 MFMA => f32 quality)
//  k_S2   : Spart[ck2][m][n] partial GEMM, grid 4 mt x 64 (c,k2)
//  k_Sred : S[m][n] = sum_ck2 Spart
//  k_scan : u[bp,n] = S[bp,30] + sum_i Ann^(2^i) @ S[bp,29-i] (early-exit)
//  k_h    : h = Aoo*k_last*v_last + Aon . u
//  k_y    : y = q . h

#define ANO_C_STR 3276800
#define ANO_K_STR 409600
#define ANO_X_STR 6400

typedef __attribute__((ext_vector_type(8))) short bf16x8;
typedef __attribute__((ext_vector_type(4))) float f32x4;
typedef __attribute__((ext_vector_type(4))) unsigned short u16x4;

__device__ __forceinline__ float4 ld4(const float* p) { return *(const float4*)p; }

__device__ __forceinline__ unsigned short f2bf(float f) {  // RNE
  unsigned u = __float_as_uint(f);
  unsigned r = (u + 0x7fffu + ((u >> 16) & 1u)) >> 16;
  return (unsigned short)r;
}
__device__ __forceinline__ float bf2f(unsigned short b) {
  return __uint_as_float(((unsigned)b) << 16);
}
// packed cvt: 2 f32 -> u32 of 2 bf16 (1 instr). Used for BOTH A and B k-pairs,
// so a lo/hi convention swap permutes both sides identically and cancels.
__device__ __forceinline__ unsigned cvtpk(float lo, float hi) {
  unsigned r;
  asm("v_cvt_pk_bf16_f32 %0, %1, %2" : "=v"(r) : "v"(lo), "v"(hi));
  return r;
}

// ---------------------------------------------------------------- k_prep
__global__ __launch_bounds__(256) void k_prep(const float* __restrict__ X,
                                              unsigned short* __restrict__ A2) {
  __shared__ float xs[512];
  const int m = blockIdx.x;
  const int tid = threadIdx.x;
  for (int f = tid; f < 512; f += 256) xs[f] = X[m * 512 + f];
  __syncthreads();
  for (int f = tid; f < 512; f += 256) {
    float v = xs[((f & 7) << 6) | (f >> 3)];
    unsigned short hi = f2bf(v);
    unsigned short lo = f2bf(v - bf2f(hi));
    A2[(size_t)m * 1536 + f] = hi;
    A2[(size_t)m * 1536 + 512 + f] = hi;
    A2[(size_t)m * 1536 + 1024 + f] = lo;
  }
}

// ---------------------------------------------------------------- k_cvtW
__global__ __launch_bounds__(128) void k_cvtW(const float* __restrict__ Km,
                                              const float* __restrict__ Qm,
                                              const float* __restrict__ Vm,
                                              unsigned short* __restrict__ Bw) {
  const int j = blockIdx.x;  // mat*512 + o
  const int mat = j >> 9, o = j & 511;
  const int r = ((o & 63) << 3) | (o >> 6);
  const float* W = ((mat == 0) ? Km : ((mat == 1) ? Qm : Vm)) + (size_t)r * 512;
  const int tid = threadIdx.x;
  float4 v = ld4(W + tid * 4);
  u16x4 hi, lo;
  float vv[4] = {v.x, v.y, v.z, v.w};
#pragma unroll
  for (int e = 0; e < 4; ++e) {
    hi[e] = f2bf(vv[e]);
    lo[e] = f2bf(vv[e] - bf2f(hi[e]));
  }
  *(u16x4*)&Bw[(size_t)j * 1536 + tid * 4] = hi;
  *(u16x4*)&Bw[(size_t)j * 1536 + 512 + tid * 4] = lo;
  *(u16x4*)&Bw[(size_t)j * 1536 + 1024 + tid * 4] = hi;
}

// ---------------------------------------------------------------- k_kqv3
__global__ __launch_bounds__(256) void k_kqv3(const unsigned short* __restrict__ A2,
                                              const unsigned short* __restrict__ Bw,
                                              float* __restrict__ kqvF) {
  __shared__ __align__(16) unsigned short Asm[128 * 64];
  __shared__ __align__(16) unsigned short Bsm[128 * 64];
  const int bid = blockIdx.x;  // 24
  const int mt = bid & 1, jt = bid >> 1;
  const int m0 = mt * 128, j0 = jt * 128;
  const int tid = threadIdx.x;
  const int lane = tid & 63;
  const int w = tid >> 6;
  const int wm = w >> 1, wn = w & 1;

  f32x4 acc[4][4];
#pragma unroll
  for (int a = 0; a < 4; ++a)
#pragma unroll
    for (int b = 0; b < 4; ++b) acc[a][b] = (f32x4)(0.f);

  for (int kc = 0; kc < 1536; kc += 64) {
#pragma unroll
    for (int cch = 0; cch < 4; ++cch) {
      int sid = cch * 256 + tid;
      int r = sid >> 3, c8 = sid & 7;
      int srcc = c8 ^ (r & 7);
      const unsigned short* ga = A2 + (size_t)(m0 + r) * 1536 + kc + srcc * 8;
      __builtin_amdgcn_global_load_lds((const __attribute__((address_space(1))) unsigned int*)ga,
                                       (__attribute__((address_space(3))) unsigned int*)(&Asm[sid * 8]),
                                       16, 0, 0);
      const unsigned short* gb = Bw + (size_t)(j0 + r) * 1536 + kc + srcc * 8;
      __builtin_amdgcn_global_load_lds((const __attribute__((address_space(1))) unsigned int*)gb,
                                       (__attribute__((address_space(3))) unsigned int*)(&Bsm[sid * 8]),
                                       16, 0, 0);
    }
    __syncthreads();
#pragma unroll
    for (int ks = 0; ks < 2; ++ks) {
      bf16x8 af[4], bfr[4];
#pragma unroll
      for (int mf = 0; mf < 4; ++mf) {
        int r = wm * 64 + mf * 16 + (lane & 15);
        int slot = (ks * 4 + (lane >> 4)) ^ (r & 7);
        af[mf] = *(const bf16x8*)&Asm[r * 64 + slot * 8];
      }
#pragma unroll
      for (int nf = 0; nf < 4; ++nf) {
        int r = wn * 64 + nf * 16 + (lane & 15);
        int slot = (ks * 4 + (lane >> 4)) ^ (r & 7);
        bfr[nf] = *(const bf16x8*)&Bsm[r * 64 + slot * 8];
      }
#pragma unroll
      for (int mf = 0; mf < 4; ++mf)
#pragma unroll
        for (int nf = 0; nf < 4; ++nf)
          acc[mf][nf] = __builtin_amdgcn_mfma_f32_16x16x32_bf16(af[mf], bfr[nf], acc[mf][nf], 0, 0, 0);
    }
    __syncthreads();
  }
#pragma unroll
  for (int mf = 0; mf < 4; ++mf)
#pragma unroll
    for (int nf = 0; nf < 4; ++nf) {
      int col = j0 + wn * 64 + nf * 16 + (lane & 15);
      int mat = col >> 9, o = col & 511;
      float* Outp = kqvF + (size_t)mat * 131072;
#pragma unroll
      for (int r = 0; r < 4; ++r) {
        int row = m0 + wm * 64 + mf * 16 + (lane >> 4) * 4 + r;
        Outp[(size_t)row * 512 + o] = acc[mf][nf][r];
      }
    }
}

// ---------------------------------------------------------------- k_S2
// Spart[ck2][m][n] = sum_{x,y} bf16(k[m, c*64+x]*v[m, k2*64+y]) * bf16(Ano[c,k2,x,y,n])
// grid 256 = mt(4, stride 64 => same-XCD siblings) x ck2(64). 256 thr, 4 waves.
// Per wave: 1 m-frag (16 rows) x 7 n-frags. Per x: B panel [112n][64y] bf16
// dbuf-staged (cvtpk + XOR-swizzled u32 writes, round-4-verified pattern).
__global__ __launch_bounds__(256) void k_S2(const float* __restrict__ kw,
                                            const float* __restrict__ vw,
                                            const float* __restrict__ Ano,
                                            float* __restrict__ Spart) {
  __shared__ float ksl[64 * 64];            // [x][m ^ (x&31)]
  __shared__ float vsl[64 * 68];            // [m][y], pad 68
  __shared__ __align__(16) unsigned Bp[2][112 * 32];  // [n][ypair swizzled]
  const int bid = blockIdx.x;
  const int mt = bid >> 6, ck2 = bid & 63;
  const int c = ck2 >> 3, k2 = ck2 & 7;
  const int m0 = mt * 64;
  const int tid = threadIdx.x;
  const int lane = tid & 63;
  const int w = tid >> 6;

  // stage k,v slices (f32)
#pragma unroll
  for (int i = 0; i < 16; ++i) {
    int g = i * 256 + tid;
    int m = g >> 6, gx = g & 63;
    ksl[gx * 64 + (m ^ (gx & 31))] = kw[(size_t)(m0 + m) * 512 + c * 64 + gx];
    vsl[m * 68 + gx] = vw[(size_t)(m0 + m) * 512 + k2 * 64 + gx];
  }

  const int y2 = tid >> 3;          // 0..31 (ypair)
  const int n0 = (tid & 7) * 14;    // col chunk
  const float* anoBase = Ano + (size_t)c * ANO_C_STR + (size_t)k2 * ANO_K_STR +
                         (size_t)y2 * 200 + n0;

  float2 br0[7], br1[7];
  {  // preload panel x=0
    const float* px = anoBase;
#pragma unroll
    for (int j = 0; j < 7; ++j) {
      int n = n0 + 2 * j;
      br0[j] = (n < 100) ? *(const float2*)(px + 2 * j) : make_float2(0.f, 0.f);
      br1[j] = (n < 100) ? *(const float2*)(px + 100 + 2 * j) : make_float2(0.f, 0.f);
    }
  }
  __syncthreads();

  f32x4 acc[7];
#pragma unroll
  for (int nf = 0; nf < 7; ++nf) acc[nf] = (f32x4)(0.f);

  for (int x = 0; x < 64; ++x) {
    // write panel x into Bp[x&1]
    unsigned* bp = &Bp[x & 1][0];
#pragma unroll
    for (int j = 0; j < 7; ++j) {
      int n = n0 + 2 * j;
      unsigned w0 = cvtpk(br0[j].x, br1[j].x);
      unsigned w1 = cvtpk(br0[j].y, br1[j].y);
      bp[n * 32 + (y2 ^ ((n & 7) << 2))] = w0;
      bp[(n + 1) * 32 + (y2 ^ (((n + 1) & 7) << 2))] = w1;
    }
    // issue loads for panel x+1 (hidden under MFMA)
    if (x < 63) {
      const float* px = anoBase + (size_t)(x + 1) * ANO_X_STR;
#pragma unroll
      for (int j = 0; j < 7; ++j) {
        int n = n0 + 2 * j;
        br0[j] = (n < 100) ? *(const float2*)(px + 2 * j) : make_float2(0.f, 0.f);
        br1[j] = (n < 100) ? *(const float2*)(px + 100 + 2 * j) : make_float2(0.f, 0.f);
      }
    }
    __syncthreads();

    // A-frags: a[m][y] = k[m,x]*v[m,y], bf16 via cvtpk (same pairing as B)
    bf16x8 af[2];
#pragma unroll
    for (int ks = 0; ks < 2; ++ks) {
      int mloc = w * 16 + (lane & 15);
      float kx = ksl[x * 64 + (mloc ^ (x & 31))];
      const float* vp = &vsl[mloc * 68 + ks * 32 + (lane >> 4) * 8];
      float4 va = ld4(vp), vb = ld4(vp + 4);
      union { unsigned u[4]; bf16x8 v; } fu;
      fu.u[0] = cvtpk(kx * va.x, kx * va.y);
      fu.u[1] = cvtpk(kx * va.z, kx * va.w);
      fu.u[2] = cvtpk(kx * vb.x, kx * vb.y);
      fu.u[3] = cvtpk(kx * vb.z, kx * vb.w);
      af[ks] = fu.v;
    }
    const unsigned short* bp16 = (const unsigned short*)bp;
#pragma unroll
    for (int nf = 0; nf < 7; ++nf) {
      int r = nf * 16 + (lane & 15);
#pragma unroll
      for (int ks = 0; ks < 2; ++ks) {
        int slot = (ks * 4 + (lane >> 4)) ^ (r & 7);
        bf16x8 bfrag = *(const bf16x8*)&bp16[r * 64 + slot * 8];
        acc[nf] = __builtin_amdgcn_mfma_f32_16x16x32_bf16(af[ks], bfrag, acc[nf], 0, 0, 0);
      }
    }
  }

#pragma unroll
  for (int nf = 0; nf < 7; ++nf) {
    int n = nf * 16 + (lane & 15);
    if (n < 100) {
#pragma unroll
      for (int rr = 0; rr < 4; ++rr) {
        int m = m0 + w * 16 + (lane >> 4) * 4 + rr;
        Spart[(size_t)ck2 * 25600 + (size_t)m * 100 + n] = acc[nf][rr];
      }
    }
  }
}

// ---------------------------------------------------------------- k_Sred
__global__ __launch_bounds__(128) void k_Sred(const float* __restrict__ Spart,
                                              float* __restrict__ S) {
  const int m = blockIdx.x;
  const int tid = threadIdx.x;
  if (tid < 100) {
    float acc = 0.f;
#pragma unroll 8
    for (int t = 0; t < 64; ++t) acc += Spart[(size_t)t * 25600 + (size_t)m * 100 + tid];
    S[m * 100 + tid] = acc;
  }
}

// ---------------------------------------------------------------- k_scan
__global__ __launch_bounds__(1024) void k_scan(const float* __restrict__ Ann,
                                               const float* __restrict__ Sg,
                                               float* __restrict__ ug) {
  __shared__ float Abuf[10000];
  __shared__ float s_s[800];
  __shared__ float u_s[800];
  __shared__ float red[16];
  __shared__ float gmax_s;
  const int tid = threadIdx.x;

  float lmax0 = 0.f;
  for (int f = tid; f < 10000; f += 1024) {
    float a = Ann[f];
    Abuf[f] = a;
    lmax0 = fmaxf(lmax0, fabsf(a));
  }
  for (int f = tid; f < 800; f += 1024) {
    int bp = f / 100, n = f - bp * 100;
    u_s[f] = Sg[(bp * 32 + 30) * 100 + n];
  }
#pragma unroll
  for (int off = 32; off > 0; off >>= 1) lmax0 = fmaxf(lmax0, __shfl_down(lmax0, off, 64));
  if ((tid & 63) == 0) red[tid >> 6] = lmax0;
  __syncthreads();
  if (tid == 0) {
    float mx = 0.f;
    for (int wv = 0; wv < 16; ++wv) mx = fmaxf(mx, red[wv]);
    gmax_s = mx;
  }
  const int ri = tid / 25;
  const int cj = tid - ri * 25;
  const bool sqact = (tid < 625);
  __syncthreads();

  for (int i = 0; i < 30; ++i) {
    const int t = 29 - i;
    for (int f = tid; f < 800; f += 1024) {
      int bp = f / 100, n = f - bp * 100;
      s_s[f] = Sg[(bp * 32 + t) * 100 + n];
    }
    __syncthreads();
    if (tid < 800) {
      int bp = tid / 100, n = tid - bp * 100;
      const float* Ar = &Abuf[n * 100];
      const float* sr = &s_s[bp * 100];
      float a0 = 0.f;
#pragma unroll
      for (int mm = 0; mm < 100; mm += 4) {
        float4 a4 = ld4(Ar + mm);
        float4 s4 = ld4(sr + mm);
        a0 += a4.x * s4.x + a4.y * s4.y + a4.z * s4.z + a4.w * s4.w;
      }
      u_s[tid] += a0;
    }
    if (i == 29) break;
    if (gmax_s < 1e-6f) break;

    float acc2[4][4];
    float lmax = 0.f;
    if (sqact) {
#pragma unroll
      for (int a = 0; a < 4; ++a)
#pragma unroll
        for (int b = 0; b < 4; ++b) acc2[a][b] = 0.f;
      for (int mm = 0; mm < 100; mm += 4) {
        float av[4][4], bv[4][4];
#pragma unroll
        for (int ii = 0; ii < 4; ++ii)
          *(float4*)&av[ii][0] = ld4(&Abuf[(ri * 4 + ii) * 100 + mm]);
#pragma unroll
        for (int mi = 0; mi < 4; ++mi)
          *(float4*)&bv[mi][0] = ld4(&Abuf[(mm + mi) * 100 + cj * 4]);
#pragma unroll
        for (int ii = 0; ii < 4; ++ii)
#pragma unroll
          for (int mi = 0; mi < 4; ++mi)
#pragma unroll
            for (int qq = 0; qq < 4; ++qq) acc2[ii][qq] += av[ii][mi] * bv[mi][qq];
      }
    }
    __syncthreads();
    if (sqact) {
#pragma unroll
      for (int ii = 0; ii < 4; ++ii) {
        float4 wv = make_float4(acc2[ii][0], acc2[ii][1], acc2[ii][2], acc2[ii][3]);
        *(float4*)&Abuf[(ri * 4 + ii) * 100 + cj * 4] = wv;
        lmax = fmaxf(lmax, fmaxf(fmaxf(fabsf(wv.x), fabsf(wv.y)), fmaxf(fabsf(wv.z), fabsf(wv.w))));
      }
    }
#pragma unroll
    for (int off = 32; off > 0; off >>= 1) lmax = fmaxf(lmax, __shfl_down(lmax, off, 64));
    if ((tid & 63) == 0) red[tid >> 6] = lmax;
    __syncthreads();
    if (tid == 0) {
      float mx = 0.f;
      for (int wv = 0; wv < 16; ++wv) mx = fmaxf(mx, red[wv]);
      gmax_s = mx;
    }
    __syncthreads();
  }
  __syncthreads();
  for (int f = tid; f < 800; f += 1024) ug[f] = u_s[f];
}

// ---------------------------------------------------------------- k_h
__global__ __launch_bounds__(256) void k_h(const float* __restrict__ Aon,
                                           const float* __restrict__ Aoo,
                                           const float* __restrict__ kw,
                                           const float* __restrict__ vw,
                                           const float* __restrict__ ug,
                                           float* __restrict__ h) {
  __shared__ float uT[100 * 8];
  __shared__ float aoo_s[64];
  __shared__ float kl_s[8];
  __shared__ float vl_s[8 * 64];
  __shared__ float part[4 * 64 * 8];
  const int bid = blockIdx.x;  // (a*8+b)*64+g
  const int g = bid & 63, b = (bid >> 6) & 7, a = bid >> 9;
  const int tid = threadIdx.x;

  for (int f = tid; f < 800; f += 256) {
    int n = f >> 3, bp = f & 7;
    uT[f] = ug[bp * 100 + n];
  }
  if (tid < 64) aoo_s[tid] = Aoo[(size_t)bid * 64 + tid];
  if (tid < 8) kl_s[tid] = kw[(size_t)(tid * 32 + 31) * 512 + a * 64 + g];
  for (int f = tid; f < 512; f += 256) {
    int bp = f >> 6, d = f & 63;
    vl_s[f] = vw[(size_t)(bp * 32 + 31) * 512 + b * 64 + d];
  }
  __syncthreads();

  const int ng = tid & 3, d = tid >> 2;
  float ar[25];
  {
    const float* basep = Aon + (size_t)(bid * 64 + d) * 100 + ng * 25;
#pragma unroll
    for (int q = 0; q < 25; ++q) ar[q] = basep[q];
  }
  float acc8[8];
#pragma unroll
  for (int bb = 0; bb < 8; ++bb) acc8[bb] = 0.f;
#pragma unroll
  for (int q = 0; q < 25; ++q) {
    int n = ng * 25 + q;
    float av = ar[q];
    float4 u0 = ld4(&uT[n * 8]);
    float4 u1 = ld4(&uT[n * 8 + 4]);
    acc8[0] += av * u0.x; acc8[1] += av * u0.y; acc8[2] += av * u0.z; acc8[3] += av * u0.w;
    acc8[4] += av * u1.x; acc8[5] += av * u1.y; acc8[6] += av * u1.z; acc8[7] += av * u1.w;
  }
  {
    float* pp = &part[(ng * 64 + d) * 8];
    *(float4*)pp = make_float4(acc8[0], acc8[1], acc8[2], acc8[3]);
    *(float4*)(pp + 4) = make_float4(acc8[4], acc8[5], acc8[6], acc8[7]);
  }
  __syncthreads();
  for (int o = tid; o < 512; o += 256) {
    int bp = o >> 6, d2 = o & 63;
    float s = aoo_s[d2] * kl_s[bp] * vl_s[bp * 64 + d2];
#pragma unroll
    for (int n2 = 0; n2 < 4; ++n2) s += part[(n2 * 64 + d2) * 8 + bp];
    h[(size_t)bp * 262144 + (size_t)bid * 64 + d2] = s;
  }
}

// ---------------------------------------------------------------- k_y
__global__ __launch_bounds__(256) void k_y(const float* __restrict__ qw,
                                           const float* __restrict__ h,
                                           float* __restrict__ out) {
  __shared__ float qT[32 * 32];
  __shared__ float Hs[32 * 64];
  const int bid = blockIdx.x;  // bp*8 + b
  const int bp = bid >> 3, b = bid & 7;
  const int tid = threadIdx.x;
  const int r2 = tid >> 4, c2 = tid & 15;
  const size_t hbase = (size_t)bp * 262144 + (size_t)b * 4096;
  float acc[2][4];
#pragma unroll
  for (int i = 0; i < 2; ++i)
#pragma unroll
    for (int q = 0; q < 4; ++q) acc[i][q] = 0.f;

  for (int kc = 0; kc < 512; kc += 32) {
    {
      int t = tid & 31, kq = tid >> 5;
      float4 qv = ld4(qw + (size_t)(bp * 32 + t) * 512 + kc + kq * 4);
      qT[(kq * 4 + 0) * 32 + t] = qv.x;
      qT[(kq * 4 + 1) * 32 + t] = qv.y;
      qT[(kq * 4 + 2) * 32 + t] = qv.z;
      qT[(kq * 4 + 3) * 32 + t] = qv.w;
    }
#pragma unroll
    for (int i2 = 0; i2 < 2; ++i2) {
      int fid = i2 * 256 + tid;
      int kk = fid >> 4, xq = (fid & 15) * 4;
      int row = kc + kk;
      int A = row >> 6, G = row & 63;
      float4 hv = ld4(h + hbase + (size_t)A * 32768 + (size_t)G * 64 + xq);
      *(float4*)&Hs[kk * 64 + xq] = hv;
    }
    __syncthreads();
#pragma unroll
    for (int kk = 0; kk < 32; ++kk) {
      float2 q2 = *(const float2*)&qT[kk * 32 + r2 * 2];
      float4 h4 = ld4(&Hs[kk * 64 + c2 * 4]);
      acc[0][0] += q2.x * h4.x; acc[0][1] += q2.x * h4.y; acc[0][2] += q2.x * h4.z; acc[0][3] += q2.x * h4.w;
      acc[1][0] += q2.y * h4.x; acc[1][1] += q2.y * h4.y; acc[1][2] += q2.y * h4.z; acc[1][3] += q2.y * h4.w;
    }
    __syncthreads();
  }
#pragma unroll
  for (int i = 0; i < 2; ++i) {
    float4 v = make_float4(acc[i][0], acc[i][1], acc[i][2], acc[i][3]);
    *(float4*)&out[(size_t)(bp * 32 + r2 * 2 + i) * 512 + b * 64 + c2 * 4] = v;
  }
}

// ---------------------------------------------------------------- launch
extern "C" void kernel_launch(void* const* d_in, const int* in_sizes, int n_in,
                              void* d_out, int out_size, void* d_ws, size_t ws_size,
                              hipStream_t stream) {
  const float* x   = (const float*)d_in[0];
  const float* K   = (const float*)d_in[1];
  const float* Q   = (const float*)d_in[2];
  const float* V   = (const float*)d_in[3];
  const float* Aoo = (const float*)d_in[4];
  const float* Ann = (const float*)d_in[5];
  const float* Aon = (const float*)d_in[6];
  const float* Ano = (const float*)d_in[7];
  float* out = (float*)d_out;

  float* ws = (float*)d_ws;
  float* kw  = ws;                                          // 131072
  float* qw  = kw + 131072;                                 // 131072
  float* vw  = qw + 131072;                                 // 131072
  float* S   = ws + 458752;                                 // 25600
  float* u   = S + 25600;                                   // 800
  unsigned short* A2  = (unsigned short*)(ws + 485152);     // 393216 u16
  unsigned short* Bw  = (unsigned short*)(ws + 681760);     // 2359296 u16
  float* h     = ws + 1861408;                              // 2097152
  float* Spart = ws + 3958560;                              // 1638400

  k_prep<<<dim3(256), dim3(256), 0, stream>>>(x, A2);
  k_cvtW<<<dim3(1536), dim3(128), 0, stream>>>(K, Q, V, Bw);
  k_kqv3<<<dim3(24), dim3(256), 0, stream>>>(A2, Bw, kw);
  k_S2<<<dim3(256), dim3(256), 0, stream>>>(kw, vw, Ano, Spart);
  k_Sred<<<dim3(256), dim3(128), 0, stream>>>(Spart, S);
  k_scan<<<dim3(1), dim3(1024), 0, stream>>>(Ann, S, u);
  k_h<<<dim3(4096), dim3(256), 0, stream>>>(Aon, Aoo, kw, vw, u, h);
  k_y<<<dim3(64), dim3(256), 0, stream>>>(qw, h, out);
}